// Round 16
// baseline (2108.335 us; speedup 1.0000x reference)
//
#include <hip/hip_runtime.h>

#define VV 50257
#define DD 50
#define TT 1024
#define BB 1024

typedef _Float16 f16;
typedef _Float16 f16x8 __attribute__((ext_vector_type(8)));
typedef float f32x4 __attribute__((ext_vector_type(4)));

__device__ __forceinline__ float sigmf(float x) { return 1.0f / (1.0f + __expf(-x)); }
__device__ __forceinline__ float tanhf_fast(float x) {
    float e = __expf(-2.0f * fabsf(x));
    return copysignf((1.0f - e) / (1.0f + e), x);
}
#define MFMA16(a, b, c) __builtin_amdgcn_mfma_f32_16x16x32_f16((a), (b), (c), 0, 0, 0)

// P1[v][j] = b1[0][j] + sum_d emb[v][d] * kx1[d][j]   (one-time, ~0.5 GFLOP)
__global__ void proj_emb(const float* __restrict__ emb, const float* __restrict__ kx1,
                         const float* __restrict__ b1, float* __restrict__ P1) {
    int j = threadIdx.x;             // 0..95
    int v0 = blockIdx.x * 8;
    #pragma unroll 1
    for (int vv = 0; vv < 8; ++vv) {
        int v = v0 + vv;
        if (v >= VV) return;
        float acc = b1[j];
        #pragma unroll
        for (int d = 0; d < DD; ++d)
            acc += emb[v * DD + d] * kx1[d * 96 + j];
        P1[v * 96 + j] = acc;
    }
}

// MFMA-batched RNN: 16 rows per block, 64 blocks, 2 waves.
// All matvecs via mfma_f32_16x16x32_f16 (A = H rows x K units, B = weights
// K x 16-col tile). State h1/h2 stays FP32 in registers; only MFMA inputs are
// f16 (h written to LDS as f16 each step; weights converted once). Gates in
// f32, identical math to the verified scalar kernels (absmax 0.0 r0-r15).
// Layouts (guide §3, m89-verified C/D): D: col=lane&15, row=(lane>>4)*4+reg.
// A: row m=lane&15, k=(lane>>4)*8+e. B: col n=lane&15, k=(lane>>4)*8+e.
//  Wave A: m(t)=h2(t-1)·kh2+b2[1] (24 MFMA, 12 N-tiles x 2 K-halves, bias via
//    C) | barrier | read x(t) frags from ring, gates -> h2(t) (f32 regs),
//    write h2 f16 -> h2l. Owns GLU head.
//  Wave B (1 step ahead): x(t)=h1(t)·kx2+b2[0] (12 MFMA) -> ring slot t&1;
//    GRU1: h1(t+1) (6 MFMA + gates, P1 values prefetched per D-layout);
//    h1 f16 -> h1l (parity slots).
// Ring slot t&1: B writes pre-bar(t), A reads post-bar(t), B rewrites pre(t+2)
// which is after bar(t+1), which A only reaches after finishing post(t). Safe.
// h2l/h1l/hf are single-wave-owned (no cross-wave access; program order).
__global__ __launch_bounds__(128, 1)
void rnn_mfma(const int* __restrict__ tokens, const float* __restrict__ P1,
              const float* __restrict__ kh1, const float* __restrict__ b1,
              const float* __restrict__ kx2, const float* __restrict__ kh2,
              const float* __restrict__ b2, const float* __restrict__ wg,
              const float* __restrict__ bg, const float* __restrict__ wd,
              const float* __restrict__ bd, float* __restrict__ out) {
    const int lane = threadIdx.x & 63;
    const int wv   = threadIdx.x >> 6;
    const int row0 = blockIdx.x * 16;
    const int cl   = lane & 15;          // A-row m / B-col n / D-col n
    const int kg   = lane >> 4;          // k-octet selector
    const int m0   = kg * 4;             // D-frag base row

    __shared__ __align__(16) f16 h2l[16][72];      // h2 state, f16 (A-owned)
    __shared__ __align__(16) f16 h1l[2][16][40];   // h1 parity slots (B-owned)
    __shared__ f32x4 xr[2][12][64];                // x-frag ring
    __shared__ float hf[16][64];                   // final h2 f32 (head)

    if (wv == 0) {
        int* z = (int*)&h2l[0][0];                 // 16*72*2/4 = 576 ints
        for (int i = lane; i < 576; i += 64) z[i] = 0;
    } else {
        int* z = (int*)&h1l[0][0][0];              // 2*16*40*2/4 = 640 ints
        for (int i = lane; i < 640; i += 64) z[i] = 0;
    }

    if (wv == 0) {
        // ---- kh2 B-frags (12 tiles x 2 K-halves) + b2[1] bias ----
        f16x8 wb[24]; float cb[12];
        #pragma unroll
        for (int nt = 0; nt < 12; ++nt) {
            cb[nt] = b2[192 + 16 * nt + cl];
            #pragma unroll
            for (int kh = 0; kh < 2; ++kh) {
                f16x8 v;
                #pragma unroll
                for (int e = 0; e < 8; ++e)
                    v[e] = (f16)kh2[(32 * kh + kg * 8 + e) * 192 + 16 * nt + cl];
                wb[nt * 2 + kh] = v;
            }
        }
        float h2o[4][4];
        #pragma unroll
        for (int a = 0; a < 4; ++a)
            #pragma unroll
            for (int b_ = 0; b_ < 4; ++b_) h2o[a][b_] = 0.f;

        #pragma unroll 1
        for (int t = 0; t < TT; ++t) {
            // m(t) = h2(t-1)·kh2 + b2[1]
            f16x8 a0 = *(const f16x8*)&h2l[cl][kg * 8];
            f16x8 a1 = *(const f16x8*)&h2l[cl][32 + kg * 8];
            f32x4 D[12];
            #pragma unroll
            for (int nt = 0; nt < 12; ++nt) {
                f32x4 c = {cb[nt], cb[nt], cb[nt], cb[nt]};
                c = MFMA16(a0, wb[nt * 2], c);
                D[nt] = MFMA16(a1, wb[nt * 2 + 1], c);
            }
            __syncthreads();
            // gates -> h2(t)
            #pragma unroll
            for (int zt = 0; zt < 4; ++zt) {
                f32x4 Xz = xr[t & 1][zt][lane];
                f32x4 Xr = xr[t & 1][4 + zt][lane];
                f32x4 Xh = xr[t & 1][8 + zt][lane];
                #pragma unroll
                for (int r = 0; r < 4; ++r) {
                    float z  = sigmf(Xz[r] + D[zt][r]);
                    float rg = sigmf(Xr[r] + D[4 + zt][r]);
                    float hh = tanhf_fast(Xh[r] + rg * D[8 + zt][r]);
                    float hn = z * h2o[zt][r] + (1.f - z) * hh;
                    h2o[zt][r] = hn;
                    h2l[m0 + r][16 * zt + cl] = (f16)hn;
                }
            }
            if (t == TT - 1) {
                #pragma unroll
                for (int zt = 0; zt < 4; ++zt)
                    #pragma unroll
                    for (int r = 0; r < 4; ++r)
                        hf[m0 + r][16 * zt + cl] = h2o[zt][r];
            }
        }
        // ---- head: GLU + dense per row (hf broadcast reads) ----
        #pragma unroll 1
        for (int m = 0; m < 16; ++m) {
            float a0 = bg[lane], a1 = bg[64 + lane], a2 = bg[128 + lane], a3 = bg[192 + lane];
            #pragma unroll 16
            for (int k = 0; k < 64; ++k) {
                float s = hf[m][k];
                a0 += s * wg[k * 256 + lane];
                a1 += s * wg[k * 256 + 64 + lane];
                a2 += s * wg[k * 256 + 128 + lane];
                a3 += s * wg[k * 256 + 192 + lane];
            }
            float g = a0 * sigmf(a2) * wd[lane] + a1 * sigmf(a3) * wd[64 + lane];
            g += __shfl_xor(g, 32); g += __shfl_xor(g, 16); g += __shfl_xor(g, 8);
            g += __shfl_xor(g, 4);  g += __shfl_xor(g, 2);  g += __shfl_xor(g, 1);
            if (lane == 0) out[row0 + m] = sigmf(g + bd[0]);
        }
    } else {
        // ---- kx2 (12 tiles) + kh1 (6 tiles) B-frags + biases ----
        f16x8 wx[12], w1[6]; float cx[12], cg[6];
        #pragma unroll
        for (int nt = 0; nt < 12; ++nt) {
            cx[nt] = b2[16 * nt + cl];
            f16x8 v;
            #pragma unroll
            for (int e = 0; e < 8; ++e)
                v[e] = (f16)kx2[(kg * 8 + e) * 192 + 16 * nt + cl];
            wx[nt] = v;
        }
        #pragma unroll
        for (int nt = 0; nt < 6; ++nt) {
            cg[nt] = b1[96 + 16 * nt + cl];
            f16x8 v;
            #pragma unroll
            for (int e = 0; e < 8; ++e)
                v[e] = (f16)kh1[(kg * 8 + e) * 96 + 16 * nt + cl];
            w1[nt] = v;
        }
        const int* tb[4];
        #pragma unroll
        for (int r = 0; r < 4; ++r) tb[r] = tokens + (row0 + m0 + r) * TT;

        float h1o[2][4];
        #pragma unroll
        for (int jt = 0; jt < 2; ++jt)
            #pragma unroll
            for (int r = 0; r < 4; ++r) h1o[jt][r] = 0.f;
        float p[2][4][3];
        int tk[4];

        // ---- prologue: h1(0) from h1(-1)=0 and p(0) ----
        #pragma unroll
        for (int r = 0; r < 4; ++r) tk[r] = tb[r][0];
        #pragma unroll
        for (int r = 0; r < 4; ++r) {
            const float* bp = P1 + tk[r] * 96 + cl;
            #pragma unroll
            for (int jt = 0; jt < 2; ++jt) {
                p[jt][r][0] = bp[16 * jt];
                p[jt][r][1] = bp[32 + 16 * jt];
                p[jt][r][2] = bp[64 + 16 * jt];
            }
        }
        {
            f16x8 af = *(const f16x8*)&h1l[1][cl][kg * 8];   // zeros
            f32x4 G[6];
            #pragma unroll
            for (int nt = 0; nt < 6; ++nt) {
                f32x4 c = {cg[nt], cg[nt], cg[nt], cg[nt]};
                G[nt] = MFMA16(af, w1[nt], c);
            }
            #pragma unroll
            for (int jt = 0; jt < 2; ++jt)
                #pragma unroll
                for (int r = 0; r < 4; ++r) {
                    float z  = sigmf(p[jt][r][0] + G[jt][r]);
                    float rg = sigmf(p[jt][r][1] + G[2 + jt][r]);
                    float hh = tanhf_fast(p[jt][r][2] + rg * G[4 + jt][r]);
                    float hn = z * h1o[jt][r] + (1.f - z) * hh;
                    h1o[jt][r] = hn;
                    h1l[0][m0 + r][16 * jt + cl] = (f16)hn;
                }
        }
        #pragma unroll
        for (int r = 0; r < 4; ++r) tk[r] = tb[r][1];

        #pragma unroll 1
        for (int t = 0; t < TT; ++t) {
            // issue p(t+1) loads (addresses from tk loaded last iter)
            if (t + 1 < TT) {
                #pragma unroll
                for (int r = 0; r < 4; ++r) {
                    const float* bp = P1 + tk[r] * 96 + cl;
                    #pragma unroll
                    for (int jt = 0; jt < 2; ++jt) {
                        p[jt][r][0] = bp[16 * jt];
                        p[jt][r][1] = bp[32 + 16 * jt];
                        p[jt][r][2] = bp[64 + 16 * jt];
                    }
                }
            }
            {   // prefetch tokens for t+2
                int t2 = (t + 2 < TT) ? (t + 2) : (TT - 1);
                #pragma unroll
                for (int r = 0; r < 4; ++r) tk[r] = tb[r][t2];
            }
            // x(t) = h1(t)·kx2 + b2[0] -> ring slot t&1
            f16x8 af = *(const f16x8*)&h1l[t & 1][cl][kg * 8];
            #pragma unroll
            for (int nt = 0; nt < 12; ++nt) {
                f32x4 c = {cx[nt], cx[nt], cx[nt], cx[nt]};
                xr[t & 1][nt][lane] = MFMA16(af, wx[nt], c);
            }
            // GRU1: h1(t) -> h1(t+1) with p(t+1)
            if (t + 1 < TT) {
                f32x4 G[6];
                #pragma unroll
                for (int nt = 0; nt < 6; ++nt) {
                    f32x4 c = {cg[nt], cg[nt], cg[nt], cg[nt]};
                    G[nt] = MFMA16(af, w1[nt], c);
                }
                #pragma unroll
                for (int jt = 0; jt < 2; ++jt)
                    #pragma unroll
                    for (int r = 0; r < 4; ++r) {
                        float z  = sigmf(p[jt][r][0] + G[jt][r]);
                        float rg = sigmf(p[jt][r][1] + G[2 + jt][r]);
                        float hh = tanhf_fast(p[jt][r][2] + rg * G[4 + jt][r]);
                        float hn = z * h1o[jt][r] + (1.f - z) * hh;
                        h1o[jt][r] = hn;
                        h1l[(t + 1) & 1][m0 + r][16 * jt + cl] = (f16)hn;
                    }
            }
            __syncthreads();
        }
    }
}

extern "C" void kernel_launch(void* const* d_in, const int* in_sizes, int n_in,
                              void* d_out, int out_size, void* d_ws, size_t ws_size,
                              hipStream_t stream) {
    const int*   tokens = (const int*)d_in[0];
    const float* emb = (const float*)d_in[1];
    const float* kx1 = (const float*)d_in[2];
    const float* kh1 = (const float*)d_in[3];
    const float* b1  = (const float*)d_in[4];
    const float* kx2 = (const float*)d_in[5];
    const float* kh2 = (const float*)d_in[6];
    const float* b2  = (const float*)d_in[7];
    const float* wg  = (const float*)d_in[8];
    const float* bg  = (const float*)d_in[9];
    const float* wd  = (const float*)d_in[10];
    const float* bd  = (const float*)d_in[11];
    float* out = (float*)d_out;
    float* P1  = (float*)d_ws;   // needs 50257*96*4 = 19.3 MB of workspace

    proj_emb<<<(VV + 7) / 8, 96, 0, stream>>>(emb, kx1, b1, P1);
    rnn_mfma<<<BB / 16, 128, 0, stream>>>(tokens, P1, kh1, b1, kx2, kh2, b2,
                                          wg, bg, wd, bd, out);
}